// Round 6
// baseline (341.055 us; speedup 1.0000x reference)
//
#include <hip/hip_runtime.h>
#include <math.h>

#define NBOX 8192
#define NW   128        // NBOX / 64
#define NF   9
#define MAXOUT 1024
#define IMG_H 360
#define IMG_W 1200
#define BEV_H 704
#define BEV_W 800

// ---- persistent device scratch (module globals). Every element fully rewritten
// every call -> deterministic across graph replays.
__device__ float g_feat[NBOX * NF];
__device__ float g_score[NBOX];           // f32 softmax score (bit-mimics np)
__device__ float g_reg[NBOX * 6];
__device__ float g_obj[NBOX * 2];
__device__ float g_bev[NBOX * 4];         // unsorted bev boxes [z1,x1,z2,x2]
__device__ float g_sbev[NBOX * 4];        // sorted by rank
__device__ float g_sarea[NBOX];
__device__ int   g_rank[NBOX];
__device__ int   g_order[NBOX];           // rank -> original index
__device__ unsigned long long g_mask[(size_t)NBOX * NW];
__device__ unsigned long long g_rownz[NW];
__device__ unsigned long long g_kept[NW];

// correctly-rounded f32 exp (double internal, single final rounding)
__device__ __forceinline__ float expf_cr(float x) { return (float)exp((double)x); }

// ---- conv(1x1,32ch)+bias+relu, then mask multiply, at one pixel.
// Accumulation order mimics numpy einsum's SSE sum-of-products:
// 4 mod-4 lane accumulators, sequential group adds, reduce (L0+L1)+(L2+L3).
__device__ __forceinline__ float conv_relu_m(const float* __restrict__ map,
                                             const float* __restrict__ w,
                                             float bias, float mask,
                                             int y, int x, int W) {
  const float* p = map + ((size_t)y * W + x) * 32;
  float L0 = 0.0f, L1 = 0.0f, L2 = 0.0f, L3 = 0.0f;
#pragma unroll
  for (int c = 0; c < 32; c += 4) {
    L0 = __fadd_rn(L0, __fmul_rn(p[c + 0], w[c + 0]));
    L1 = __fadd_rn(L1, __fmul_rn(p[c + 1], w[c + 1]));
    L2 = __fadd_rn(L2, __fmul_rn(p[c + 2], w[c + 2]));
    L3 = __fadd_rn(L3, __fmul_rn(p[c + 3], w[c + 3]));
  }
  float A = __fadd_rn(L0, L1);
  float B = __fadd_rn(L2, L3);
  float conv = __fadd_rn(A, B);
  conv = __fadd_rn(conv, bias);
  float r = fmaxf(conv, 0.0f);
  return __fmul_rn(mask, r);              // (mask * x)[pixel], mask applied to map
}

// ---- one bilinear sample of the masked conv map, f32 ops in np expression order
__device__ __forceinline__ float sample_map(const float* __restrict__ map, int H, int W,
                                            const float* __restrict__ w, float bias, float mask,
                                            float y1, float x1, float y2, float x2,
                                            int gy, int gx) {
  const float tt0 = 0.0f, tt1 = 0.5f, tt2 = 1.0f;   // arange(3)/2 in f32, exact
  float ty = (gy == 0) ? tt0 : (gy == 1 ? tt1 : tt2);
  float tx = (gx == 0) ? tt0 : (gx == 1 ? tt1 : tt2);
  float ys = __fmul_rn(__fadd_rn(y1, __fmul_rn(__fsub_rn(y2, y1), ty)), (float)(H - 1));
  float xs = __fmul_rn(__fadd_rn(x1, __fmul_rn(__fsub_rn(x2, x1), tx)), (float)(W - 1));
  bool valid = (ys >= 0.0f) && (ys <= (float)(H - 1)) && (xs >= 0.0f) && (xs <= (float)(W - 1));
  if (!valid) return 0.0f;
  float y0 = floorf(ys), x0 = floorf(xs);
  float wy = __fsub_rn(ys, y0);
  float wx = __fsub_rn(xs, x0);
  int y0i = (int)fminf(fmaxf(y0, 0.0f), (float)(H - 1));
  int y1i = (int)fminf(fmaxf(__fadd_rn(y0, 1.0f), 0.0f), (float)(H - 1));
  int x0i = (int)fminf(fmaxf(x0, 0.0f), (float)(W - 1));
  int x1i = (int)fminf(fmaxf(__fadd_rn(x0, 1.0f), 0.0f), (float)(W - 1));
  float g00 = conv_relu_m(map, w, bias, mask, y0i, x0i, W);
  float g01 = conv_relu_m(map, w, bias, mask, y0i, x1i, W);
  float g10 = conv_relu_m(map, w, bias, mask, y1i, x0i, W);
  float g11 = conv_relu_m(map, w, bias, mask, y1i, x1i, W);
  float a = __fsub_rn(1.0f, wy);
  float b = __fsub_rn(1.0f, wx);
  float t1 = __fmul_rn(__fmul_rn(g00, a), b);
  float t2 = __fmul_rn(__fmul_rn(g01, a), wx);
  float t3 = __fmul_rn(__fmul_rn(g10, wy), b);
  float t4 = __fmul_rn(__fmul_rn(g11, wy), wx);
  return __fadd_rn(__fadd_rn(__fadd_rn(t1, t2), t3), t4);
}

// ---- K1: one thread per (box, sample); fused ROI feature (all f32) ----
__global__ __launch_bounds__(256) void roi_feat_kernel(
    const float* __restrict__ img_map, const float* __restrict__ bev_map,
    const float* __restrict__ anc_img, const float* __restrict__ anc_bev,
    const float* __restrict__ w_img, const float* __restrict__ b_img,
    const float* __restrict__ w_bev, const float* __restrict__ b_bev,
    const float* __restrict__ img_mask, const float* __restrict__ bev_mask) {
  int t = blockIdx.x * 256 + threadIdx.x;          // 73728 threads exactly
  int box = t / NF, s = t % NF;
  int gy = s / 3, gx = s % 3;
  const float* Ai = anc_img + (size_t)box * 5;     // cols: [0, x1, y1, x2, y2]
  const float* Ab = anc_bev + (size_t)box * 5;
  float mi = img_mask[0], mb = bev_mask[0];
  float vi = sample_map(img_map, IMG_H, IMG_W, w_img, b_img[0], mi,
                        Ai[2], Ai[1], Ai[4], Ai[3], gy, gx);
  float vb = sample_map(bev_map, BEV_H, BEV_W, w_bev, b_bev[0], mb,
                        Ab[2], Ab[1], Ab[4], Ab[3], gy, gx);
  g_feat[t] = __fdiv_rn(__fadd_rn(vi, vb), __fadd_rn(mi, mb));
}

// ---- K2: per-box head, f32 with BLAS-style sequential-FMA matmuls ----
__global__ __launch_bounds__(256) void head_kernel(
    const float* __restrict__ fa,
    const float* __restrict__ w_obj, const float* __restrict__ b_obj,
    const float* __restrict__ w_off, const float* __restrict__ b_off) {
  int i = blockIdx.x * 256 + threadIdx.x;
  if (i >= NBOX) return;
  float f[NF];
#pragma unroll
  for (int k = 0; k < NF; ++k) f[k] = g_feat[(size_t)i * NF + k];

  float o0 = 0.0f, o1 = 0.0f;
#pragma unroll
  for (int k = 0; k < NF; ++k) {
    o0 = fmaf(f[k], w_obj[k * 2 + 0], o0);
    o1 = fmaf(f[k], w_obj[k * 2 + 1], o1);
  }
  o0 = __fadd_rn(o0, b_obj[0]);
  o1 = __fadd_rn(o1, b_obj[1]);

  float off[6];
#pragma unroll
  for (int m = 0; m < 6; ++m) {
    float s = 0.0f;
#pragma unroll
    for (int k = 0; k < NF; ++k) s = fmaf(f[k], w_off[k * 6 + m], s);
    off[m] = __fadd_rn(s, b_off[m]);
  }

  float reg[6];
#pragma unroll
  for (int k = 0; k < 3; ++k)
    reg[k] = __fadd_rn(fa[i * 6 + k], __fmul_rn(off[k], fa[i * 6 + 3 + k]));
#pragma unroll
  for (int k = 0; k < 3; ++k)
    reg[3 + k] = __fmul_rn(fa[i * 6 + 3 + k], expf_cr(off[3 + k]));

#pragma unroll
  for (int k = 0; k < 6; ++k) g_reg[i * 6 + k] = reg[k];
  g_obj[i * 2 + 0] = o0;
  g_obj[i * 2 + 1] = o1;

  // softmax(objectness)[:,1] in f32, np op order: max, sub, exp, sum, div
  float m  = fmaxf(o0, o1);
  float d0 = __fsub_rn(o0, m);
  float d1 = __fsub_rn(o1, m);
  float e0 = expf_cr(d0);
  float e1 = expf_cr(d1);
  float sm = __fadd_rn(e0, e1);
  g_score[i] = __fdiv_rn(e1, sm);

  float cx = reg[0], cz = reg[2], dx = reg[3], dz = reg[5];
  float dxh = __fdiv_rn(dx, 2.0f);
  float dzh = __fdiv_rn(dz, 2.0f);
  g_bev[i * 4 + 0] = __fsub_rn(70.0f, __fadd_rn(cz, dzh));              // bz1
  g_bev[i * 4 + 1] = __fsub_rn(__fsub_rn(cx, dxh), -40.0f);             // bx1
  g_bev[i * 4 + 2] = __fsub_rn(70.0f, __fsub_rn(cz, dzh));              // bz2
  g_bev[i * 4 + 3] = __fsub_rn(__fadd_rn(cx, dxh), -40.0f);             // bx2
}

// ---- K3: exact stable descending rank on f32 scores (ties -> index asc) ----
__global__ __launch_bounds__(256) void rank_kernel() {
  __shared__ float kj[NBOX];               // 32 KiB
  int tid = threadIdx.x;
  int i = blockIdx.x * 256 + tid;
  for (int k = tid; k < NBOX; k += 256) kj[k] = g_score[k];
  __syncthreads();
  float ki = kj[i];
  int cnt = 0;
  for (int j = 0; j < NBOX; ++j) {
    float v = kj[j];
    cnt += (v > ki) || (v == ki && j < i);
  }
  g_rank[i] = cnt;
}

// ---- K3b: scatter to sorted order; area in f32 (np op order) ----
__global__ __launch_bounds__(256) void scatter_kernel() {
  int i = blockIdx.x * 256 + threadIdx.x;
  if (i >= NBOX) return;
  int r = g_rank[i];
  g_order[r] = i;
  float b0 = g_bev[i * 4 + 0], b1 = g_bev[i * 4 + 1];
  float b2 = g_bev[i * 4 + 2], b3 = g_bev[i * 4 + 3];
  g_sbev[r * 4 + 0] = b0; g_sbev[r * 4 + 1] = b1;
  g_sbev[r * 4 + 2] = b2; g_sbev[r * 4 + 3] = b3;
  g_sarea[r] = __fmul_rn(__fsub_rn(b2, b0), __fsub_rn(b3, b1));
}

// ---- K4: 64x64 IoU bitmask tiles in f32; lower triangle explicitly zeroed ----
__global__ __launch_bounds__(64) void mask_kernel() {
  int c = blockIdx.x, r = blockIdx.y;
  int lane = threadIdx.x;
  int i = r * 64 + lane;
  if (c < r) {
    g_mask[(size_t)i * NW + c] = 0ull;
    return;
  }
  __shared__ float sb[64 * 5];
  {
    int j = c * 64 + lane;
    sb[lane * 5 + 0] = g_sbev[j * 4 + 0];
    sb[lane * 5 + 1] = g_sbev[j * 4 + 1];
    sb[lane * 5 + 2] = g_sbev[j * 4 + 2];
    sb[lane * 5 + 3] = g_sbev[j * 4 + 3];
    sb[lane * 5 + 4] = g_sarea[j];
  }
  __syncthreads();
  float y1 = g_sbev[i * 4 + 0], x1 = g_sbev[i * 4 + 1];
  float y2 = g_sbev[i * 4 + 2], x2 = g_sbev[i * 4 + 3];
  float ai = g_sarea[i];
  unsigned long long bits = 0ull;
  int jbase = c * 64;
  for (int k = 0; k < 64; ++k) {
    int j = jbase + k;
    float by1 = sb[k * 5 + 0], bx1 = sb[k * 5 + 1];
    float by2 = sb[k * 5 + 2], bx2 = sb[k * 5 + 3], aj = sb[k * 5 + 4];
    // np op order: wh = max(br-tl,0); inter = wh0*wh1;
    // iou = inter / (ai + aj - inter + 1e-9); over = iou > 0.8
    float ih = fmaxf(__fsub_rn(fminf(y2, by2), fmaxf(y1, by1)), 0.0f);
    float iw = fmaxf(__fsub_rn(fminf(x2, bx2), fmaxf(x1, bx1)), 0.0f);
    float inter = __fmul_rn(ih, iw);
    float t1 = __fadd_rn(ai, aj);
    float t2 = __fsub_rn(t1, inter);
    float t3 = __fadd_rn(t2, 1e-9f);
    float iou = __fdiv_rn(inter, t3);
    bool over = (j > i) && (iou > 0.8f);
    bits |= over ? (1ull << k) : 0ull;
  }
  g_mask[(size_t)i * NW + c] = bits;
}

// ---- K4b: per-row nonzero flags via ballot ----
__global__ __launch_bounds__(64) void rownz_kernel() {
  int w = blockIdx.x, lane = threadIdx.x;
  int i = w * 64 + lane;
  const unsigned long long* row = &g_mask[(size_t)i * NW];
  unsigned long long nz = 0ull;
  for (int c = 0; c < NW; ++c) nz |= row[c];
  unsigned long long m = __ballot(nz != 0ull);
  if (lane == 0) g_rownz[w] = m;
}

// ---- K5: greedy scan; remv in LDS, plain barriers ----
__global__ __launch_bounds__(64) void scan_kernel() {
  __shared__ unsigned long long remv[NW];
  int lane = threadIdx.x;
  remv[lane] = 0ull;
  remv[64 + lane] = 0ull;
  __syncthreads();
  for (int w = 0; w < NW; ++w) {
    unsigned long long rn = g_rownz[w];
    unsigned long long cur = remv[w];
    unsigned long long todo = rn & ~cur;
    while (todo) {
      int b = __builtin_ctzll(todo);
      todo &= todo - 1;
      const unsigned long long* row = &g_mask[(size_t)(w * 64 + b) * NW];
      unsigned long long r0 = row[lane], r1 = row[64 + lane];
      remv[lane]      |= r0;
      remv[64 + lane] |= r1;
      __syncthreads();
      cur = remv[w];
      todo &= ~cur;
    }
    if (lane == 0) g_kept[w] = ~cur;
  }
}

// ---- K6: sel = kept positions asc, then suppressed asc; gather outputs ----
__global__ __launch_bounds__(256) void select_gather_kernel(float* __restrict__ out) {
  __shared__ int pk[NW], ps[NW];
  __shared__ int totK;
  __shared__ int tidx[MAXOUT];
  int tid = threadIdx.x;
  if (tid < NW) {
    pk[tid] = __popcll(g_kept[tid]);
    ps[tid] = 64 - pk[tid];
  }
  __syncthreads();
  if (tid == 0) {
    int s = 0;
    for (int w = 0; w < NW; ++w) { int t = pk[w]; pk[w] = s; s += t; }
    totK = s;
    s = 0;
    for (int w = 0; w < NW; ++w) { int t = ps[w]; ps[w] = s; s += t; }
  }
  __syncthreads();
  if (tid < NW) {
    unsigned long long kw = g_kept[tid];
    int rk = pk[tid], rs = totK + ps[tid];
    for (int b = 0; b < 64; ++b) {
      int pos = tid * 64 + b;
      if ((kw >> b) & 1ull) {
        if (rk < MAXOUT) tidx[rk] = g_order[pos];
        rk++;
      } else {
        if (rs < MAXOUT) tidx[rs] = g_order[pos];
        rs++;
      }
    }
  }
  __syncthreads();
  for (int k = tid; k < MAXOUT; k += 256) {
    int ti = tidx[k];
#pragma unroll
    for (int m = 0; m < 6; ++m) out[k * 6 + m] = g_reg[ti * 6 + m];
    out[MAXOUT * 6 + k * 2 + 0] = g_obj[ti * 2 + 0];
    out[MAXOUT * 6 + k * 2 + 1] = g_obj[ti * 2 + 1];
  }
}

extern "C" void kernel_launch(void* const* d_in, const int* in_sizes, int n_in,
                              void* d_out, int out_size, void* d_ws, size_t ws_size,
                              hipStream_t stream) {
  const float* img_map  = (const float*)d_in[0];
  const float* bev_map  = (const float*)d_in[1];
  const float* anc_img  = (const float*)d_in[2];
  const float* anc_bev  = (const float*)d_in[3];
  const float* fa       = (const float*)d_in[4];
  const float* w_img    = (const float*)d_in[5];
  const float* b_img    = (const float*)d_in[6];
  const float* w_bev    = (const float*)d_in[7];
  const float* b_bev    = (const float*)d_in[8];
  const float* w_obj    = (const float*)d_in[9];
  const float* b_obj    = (const float*)d_in[10];
  const float* w_off    = (const float*)d_in[11];
  const float* b_off    = (const float*)d_in[12];
  const float* img_mask = (const float*)d_in[13];
  const float* bev_mask = (const float*)d_in[14];
  float* out = (float*)d_out;

  roi_feat_kernel<<<dim3(288), dim3(256), 0, stream>>>(
      img_map, bev_map, anc_img, anc_bev, w_img, b_img, w_bev, b_bev, img_mask, bev_mask);
  head_kernel<<<dim3(32), dim3(256), 0, stream>>>(fa, w_obj, b_obj, w_off, b_off);
  rank_kernel<<<dim3(32), dim3(256), 0, stream>>>();
  scatter_kernel<<<dim3(32), dim3(256), 0, stream>>>();
  mask_kernel<<<dim3(128, 128), dim3(64), 0, stream>>>();
  rownz_kernel<<<dim3(128), dim3(64), 0, stream>>>();
  scan_kernel<<<dim3(1), dim3(64), 0, stream>>>();
  select_gather_kernel<<<dim3(1), dim3(256), 0, stream>>>(out);
}

// Round 7
// 157.221 us; speedup vs baseline: 2.1693x; 2.1693x over previous
//
#include <hip/hip_runtime.h>
#include <math.h>

#define NBOX 8192
#define NW   128        // NBOX / 64
#define NF   9
#define MAXOUT 1024
#define IMG_H 360
#define IMG_W 1200
#define BEV_H 704
#define BEV_W 800

// ---- persistent device scratch (module globals). Every element fully rewritten
// every call -> deterministic across graph replays.
__device__ float g_feat[NBOX * NF];
__device__ float g_score[NBOX];           // f32 softmax score (bit-mimics np)
__device__ float g_reg[NBOX * 6];
__device__ float g_obj[NBOX * 2];
__device__ float g_bev[NBOX * 4];         // unsorted bev boxes [z1,x1,z2,x2]
__device__ float g_sbev[NBOX * 4];        // sorted by rank
__device__ float g_sarea[NBOX];
__device__ int   g_rank[NBOX];
__device__ int   g_order[NBOX];           // rank -> original index
__device__ unsigned long long g_mask[(size_t)NBOX * NW];
__device__ unsigned long long g_rownz[NW];
__device__ unsigned long long g_kept[NW];

// correctly-rounded f32 exp (double internal, single final rounding)
__device__ __forceinline__ float expf_cr(float x) { return (float)exp((double)x); }

// ---- conv(1x1,32ch)+bias+relu, then mask multiply, at one pixel.
// Accumulation order mimics numpy einsum's SSE sum-of-products:
// 4 mod-4 lane accumulators, sequential group adds, reduce (L0+L1)+(L2+L3).
__device__ __forceinline__ float conv_relu_m(const float* __restrict__ map,
                                             const float* __restrict__ w,
                                             float bias, float mask,
                                             int y, int x, int W) {
  const float* p = map + ((size_t)y * W + x) * 32;
  float L0 = 0.0f, L1 = 0.0f, L2 = 0.0f, L3 = 0.0f;
#pragma unroll
  for (int c = 0; c < 32; c += 4) {
    L0 = __fadd_rn(L0, __fmul_rn(p[c + 0], w[c + 0]));
    L1 = __fadd_rn(L1, __fmul_rn(p[c + 1], w[c + 1]));
    L2 = __fadd_rn(L2, __fmul_rn(p[c + 2], w[c + 2]));
    L3 = __fadd_rn(L3, __fmul_rn(p[c + 3], w[c + 3]));
  }
  float A = __fadd_rn(L0, L1);
  float B = __fadd_rn(L2, L3);
  float conv = __fadd_rn(A, B);
  conv = __fadd_rn(conv, bias);
  float r = fmaxf(conv, 0.0f);
  return __fmul_rn(mask, r);              // (mask * x)[pixel], mask applied to map
}

// ---- one bilinear sample of the masked conv map, f32 ops in np expression order
__device__ __forceinline__ float sample_map(const float* __restrict__ map, int H, int W,
                                            const float* __restrict__ w, float bias, float mask,
                                            float y1, float x1, float y2, float x2,
                                            int gy, int gx) {
  const float tt0 = 0.0f, tt1 = 0.5f, tt2 = 1.0f;   // arange(3)/2 in f32, exact
  float ty = (gy == 0) ? tt0 : (gy == 1 ? tt1 : tt2);
  float tx = (gx == 0) ? tt0 : (gx == 1 ? tt1 : tt2);
  float ys = __fmul_rn(__fadd_rn(y1, __fmul_rn(__fsub_rn(y2, y1), ty)), (float)(H - 1));
  float xs = __fmul_rn(__fadd_rn(x1, __fmul_rn(__fsub_rn(x2, x1), tx)), (float)(W - 1));
  bool valid = (ys >= 0.0f) && (ys <= (float)(H - 1)) && (xs >= 0.0f) && (xs <= (float)(W - 1));
  if (!valid) return 0.0f;
  float y0 = floorf(ys), x0 = floorf(xs);
  float wy = __fsub_rn(ys, y0);
  float wx = __fsub_rn(xs, x0);
  int y0i = (int)fminf(fmaxf(y0, 0.0f), (float)(H - 1));
  int y1i = (int)fminf(fmaxf(__fadd_rn(y0, 1.0f), 0.0f), (float)(H - 1));
  int x0i = (int)fminf(fmaxf(x0, 0.0f), (float)(W - 1));
  int x1i = (int)fminf(fmaxf(__fadd_rn(x0, 1.0f), 0.0f), (float)(W - 1));
  float g00 = conv_relu_m(map, w, bias, mask, y0i, x0i, W);
  float g01 = conv_relu_m(map, w, bias, mask, y0i, x1i, W);
  float g10 = conv_relu_m(map, w, bias, mask, y1i, x0i, W);
  float g11 = conv_relu_m(map, w, bias, mask, y1i, x1i, W);
  float a = __fsub_rn(1.0f, wy);
  float b = __fsub_rn(1.0f, wx);
  float t1 = __fmul_rn(__fmul_rn(g00, a), b);
  float t2 = __fmul_rn(__fmul_rn(g01, a), wx);
  float t3 = __fmul_rn(__fmul_rn(g10, wy), b);
  float t4 = __fmul_rn(__fmul_rn(g11, wy), wx);
  return __fadd_rn(__fadd_rn(__fadd_rn(t1, t2), t3), t4);
}

// ---- K1: one thread per (box, sample); fused ROI feature (all f32) ----
__global__ __launch_bounds__(256) void roi_feat_kernel(
    const float* __restrict__ img_map, const float* __restrict__ bev_map,
    const float* __restrict__ anc_img, const float* __restrict__ anc_bev,
    const float* __restrict__ w_img, const float* __restrict__ b_img,
    const float* __restrict__ w_bev, const float* __restrict__ b_bev,
    const float* __restrict__ img_mask, const float* __restrict__ bev_mask) {
  int t = blockIdx.x * 256 + threadIdx.x;          // 73728 threads exactly
  int box = t / NF, s = t % NF;
  int gy = s / 3, gx = s % 3;
  const float* Ai = anc_img + (size_t)box * 5;     // cols: [0, x1, y1, x2, y2]
  const float* Ab = anc_bev + (size_t)box * 5;
  float mi = img_mask[0], mb = bev_mask[0];
  float vi = sample_map(img_map, IMG_H, IMG_W, w_img, b_img[0], mi,
                        Ai[2], Ai[1], Ai[4], Ai[3], gy, gx);
  float vb = sample_map(bev_map, BEV_H, BEV_W, w_bev, b_bev[0], mb,
                        Ab[2], Ab[1], Ab[4], Ab[3], gy, gx);
  g_feat[t] = __fdiv_rn(__fadd_rn(vi, vb), __fadd_rn(mi, mb));
}

// ---- K2: per-box head, f32 with BLAS-style sequential-FMA matmuls.
// Also zeroes g_rank[i] for the atomic rank pass that follows. ----
__global__ __launch_bounds__(256) void head_kernel(
    const float* __restrict__ fa,
    const float* __restrict__ w_obj, const float* __restrict__ b_obj,
    const float* __restrict__ w_off, const float* __restrict__ b_off) {
  int i = blockIdx.x * 256 + threadIdx.x;
  if (i >= NBOX) return;
  g_rank[i] = 0;
  float f[NF];
#pragma unroll
  for (int k = 0; k < NF; ++k) f[k] = g_feat[(size_t)i * NF + k];

  float o0 = 0.0f, o1 = 0.0f;
#pragma unroll
  for (int k = 0; k < NF; ++k) {
    o0 = fmaf(f[k], w_obj[k * 2 + 0], o0);
    o1 = fmaf(f[k], w_obj[k * 2 + 1], o1);
  }
  o0 = __fadd_rn(o0, b_obj[0]);
  o1 = __fadd_rn(o1, b_obj[1]);

  float off[6];
#pragma unroll
  for (int m = 0; m < 6; ++m) {
    float s = 0.0f;
#pragma unroll
    for (int k = 0; k < NF; ++k) s = fmaf(f[k], w_off[k * 6 + m], s);
    off[m] = __fadd_rn(s, b_off[m]);
  }

  float reg[6];
#pragma unroll
  for (int k = 0; k < 3; ++k)
    reg[k] = __fadd_rn(fa[i * 6 + k], __fmul_rn(off[k], fa[i * 6 + 3 + k]));
#pragma unroll
  for (int k = 0; k < 3; ++k)
    reg[3 + k] = __fmul_rn(fa[i * 6 + 3 + k], expf_cr(off[3 + k]));

#pragma unroll
  for (int k = 0; k < 6; ++k) g_reg[i * 6 + k] = reg[k];
  g_obj[i * 2 + 0] = o0;
  g_obj[i * 2 + 1] = o1;

  // softmax(objectness)[:,1] in f32, np op order: max, sub, exp, sum, div
  float m  = fmaxf(o0, o1);
  float d0 = __fsub_rn(o0, m);
  float d1 = __fsub_rn(o1, m);
  float e0 = expf_cr(d0);
  float e1 = expf_cr(d1);
  float sm = __fadd_rn(e0, e1);
  g_score[i] = __fdiv_rn(e1, sm);

  float cx = reg[0], cz = reg[2], dx = reg[3], dz = reg[5];
  float dxh = __fdiv_rn(dx, 2.0f);
  float dzh = __fdiv_rn(dz, 2.0f);
  g_bev[i * 4 + 0] = __fsub_rn(70.0f, __fadd_rn(cz, dzh));              // bz1
  g_bev[i * 4 + 1] = __fsub_rn(__fsub_rn(cx, dxh), -40.0f);             // bx1
  g_bev[i * 4 + 2] = __fsub_rn(70.0f, __fsub_rn(cz, dzh));              // bz2
  g_bev[i * 4 + 3] = __fsub_rn(__fadd_rn(cx, dxh), -40.0f);             // bx2
}

// ---- K3: exact stable descending rank on f32 scores, 2-D tiled.
// Block (ib, jc) counts j in [jc*256, jc*256+256) for i in [ib*256, ...).
// Integer atomicAdd partial sums: associative -> deterministic. ----
__global__ __launch_bounds__(256) void rank_kernel() {
  __shared__ float kj[256];
  int tid = threadIdx.x;
  int i = blockIdx.x * 256 + tid;
  int jbase = blockIdx.y * 256;
  kj[tid] = g_score[jbase + tid];
  float ki = g_score[i];
  __syncthreads();
  int cnt = 0;
#pragma unroll 8
  for (int k = 0; k < 256; ++k) {
    float v = kj[k];
    int j = jbase + k;
    cnt += (v > ki) || (v == ki && j < i);
  }
  atomicAdd(&g_rank[i], cnt);
}

// ---- K3b: scatter to sorted order; area in f32 (np op order) ----
__global__ __launch_bounds__(256) void scatter_kernel() {
  int i = blockIdx.x * 256 + threadIdx.x;
  if (i >= NBOX) return;
  int r = g_rank[i];
  g_order[r] = i;
  float b0 = g_bev[i * 4 + 0], b1 = g_bev[i * 4 + 1];
  float b2 = g_bev[i * 4 + 2], b3 = g_bev[i * 4 + 3];
  g_sbev[r * 4 + 0] = b0; g_sbev[r * 4 + 1] = b1;
  g_sbev[r * 4 + 2] = b2; g_sbev[r * 4 + 3] = b3;
  g_sarea[r] = __fmul_rn(__fsub_rn(b2, b0), __fsub_rn(b3, b1));
}

// ---- K4: 64x64 IoU bitmask tiles in f32; lower triangle explicitly zeroed ----
__global__ __launch_bounds__(64) void mask_kernel() {
  int c = blockIdx.x, r = blockIdx.y;
  int lane = threadIdx.x;
  int i = r * 64 + lane;
  if (c < r) {
    g_mask[(size_t)i * NW + c] = 0ull;
    return;
  }
  __shared__ float sb[64 * 5];
  {
    int j = c * 64 + lane;
    sb[lane * 5 + 0] = g_sbev[j * 4 + 0];
    sb[lane * 5 + 1] = g_sbev[j * 4 + 1];
    sb[lane * 5 + 2] = g_sbev[j * 4 + 2];
    sb[lane * 5 + 3] = g_sbev[j * 4 + 3];
    sb[lane * 5 + 4] = g_sarea[j];
  }
  __syncthreads();
  float y1 = g_sbev[i * 4 + 0], x1 = g_sbev[i * 4 + 1];
  float y2 = g_sbev[i * 4 + 2], x2 = g_sbev[i * 4 + 3];
  float ai = g_sarea[i];
  unsigned long long bits = 0ull;
  int jbase = c * 64;
  for (int k = 0; k < 64; ++k) {
    int j = jbase + k;
    float by1 = sb[k * 5 + 0], bx1 = sb[k * 5 + 1];
    float by2 = sb[k * 5 + 2], bx2 = sb[k * 5 + 3], aj = sb[k * 5 + 4];
    // np op order: wh = max(br-tl,0); inter = wh0*wh1;
    // iou = inter / (ai + aj - inter + 1e-9); over = iou > 0.8
    float ih = fmaxf(__fsub_rn(fminf(y2, by2), fmaxf(y1, by1)), 0.0f);
    float iw = fmaxf(__fsub_rn(fminf(x2, bx2), fmaxf(x1, bx1)), 0.0f);
    float inter = __fmul_rn(ih, iw);
    float t1 = __fadd_rn(ai, aj);
    float t2 = __fsub_rn(t1, inter);
    float t3 = __fadd_rn(t2, 1e-9f);
    float iou = __fdiv_rn(inter, t3);
    bool over = (j > i) && (iou > 0.8f);
    bits |= over ? (1ull << k) : 0ull;
  }
  g_mask[(size_t)i * NW + c] = bits;
}

// ---- K4b: per-row nonzero flags via ballot ----
__global__ __launch_bounds__(64) void rownz_kernel() {
  int w = blockIdx.x, lane = threadIdx.x;
  int i = w * 64 + lane;
  const unsigned long long* row = &g_mask[(size_t)i * NW];
  unsigned long long nz = 0ull;
  for (int c = 0; c < NW; ++c) nz |= row[c];
  unsigned long long m = __ballot(nz != 0ull);
  if (lane == 0) g_rownz[w] = m;
}

// ---- K5: greedy scan; remv in LDS, plain barriers ----
__global__ __launch_bounds__(64) void scan_kernel() {
  __shared__ unsigned long long remv[NW];
  int lane = threadIdx.x;
  remv[lane] = 0ull;
  remv[64 + lane] = 0ull;
  __syncthreads();
  for (int w = 0; w < NW; ++w) {
    unsigned long long rn = g_rownz[w];
    unsigned long long cur = remv[w];
    unsigned long long todo = rn & ~cur;
    while (todo) {
      int b = __builtin_ctzll(todo);
      todo &= todo - 1;
      const unsigned long long* row = &g_mask[(size_t)(w * 64 + b) * NW];
      unsigned long long r0 = row[lane], r1 = row[64 + lane];
      remv[lane]      |= r0;
      remv[64 + lane] |= r1;
      __syncthreads();
      cur = remv[w];
      todo &= ~cur;
    }
    if (lane == 0) g_kept[w] = ~cur;
  }
}

// ---- K6: sel = kept positions asc, then suppressed asc; gather outputs ----
__global__ __launch_bounds__(256) void select_gather_kernel(float* __restrict__ out) {
  __shared__ int pk[NW], ps[NW];
  __shared__ int totK;
  __shared__ int tidx[MAXOUT];
  int tid = threadIdx.x;
  if (tid < NW) {
    pk[tid] = __popcll(g_kept[tid]);
    ps[tid] = 64 - pk[tid];
  }
  __syncthreads();
  if (tid == 0) {
    int s = 0;
    for (int w = 0; w < NW; ++w) { int t = pk[w]; pk[w] = s; s += t; }
    totK = s;
    s = 0;
    for (int w = 0; w < NW; ++w) { int t = ps[w]; ps[w] = s; s += t; }
  }
  __syncthreads();
  if (tid < NW) {
    unsigned long long kw = g_kept[tid];
    int rk = pk[tid], rs = totK + ps[tid];
    for (int b = 0; b < 64; ++b) {
      int pos = tid * 64 + b;
      if ((kw >> b) & 1ull) {
        if (rk < MAXOUT) tidx[rk] = g_order[pos];
        rk++;
      } else {
        if (rs < MAXOUT) tidx[rs] = g_order[pos];
        rs++;
      }
    }
  }
  __syncthreads();
  for (int k = tid; k < MAXOUT; k += 256) {
    int ti = tidx[k];
#pragma unroll
    for (int m = 0; m < 6; ++m) out[k * 6 + m] = g_reg[ti * 6 + m];
    out[MAXOUT * 6 + k * 2 + 0] = g_obj[ti * 2 + 0];
    out[MAXOUT * 6 + k * 2 + 1] = g_obj[ti * 2 + 1];
  }
}

extern "C" void kernel_launch(void* const* d_in, const int* in_sizes, int n_in,
                              void* d_out, int out_size, void* d_ws, size_t ws_size,
                              hipStream_t stream) {
  const float* img_map  = (const float*)d_in[0];
  const float* bev_map  = (const float*)d_in[1];
  const float* anc_img  = (const float*)d_in[2];
  const float* anc_bev  = (const float*)d_in[3];
  const float* fa       = (const float*)d_in[4];
  const float* w_img    = (const float*)d_in[5];
  const float* b_img    = (const float*)d_in[6];
  const float* w_bev    = (const float*)d_in[7];
  const float* b_bev    = (const float*)d_in[8];
  const float* w_obj    = (const float*)d_in[9];
  const float* b_obj    = (const float*)d_in[10];
  const float* w_off    = (const float*)d_in[11];
  const float* b_off    = (const float*)d_in[12];
  const float* img_mask = (const float*)d_in[13];
  const float* bev_mask = (const float*)d_in[14];
  float* out = (float*)d_out;

  roi_feat_kernel<<<dim3(288), dim3(256), 0, stream>>>(
      img_map, bev_map, anc_img, anc_bev, w_img, b_img, w_bev, b_bev, img_mask, bev_mask);
  head_kernel<<<dim3(32), dim3(256), 0, stream>>>(fa, w_obj, b_obj, w_off, b_off);
  rank_kernel<<<dim3(32, 32), dim3(256), 0, stream>>>();
  scatter_kernel<<<dim3(32), dim3(256), 0, stream>>>();
  mask_kernel<<<dim3(128, 128), dim3(64), 0, stream>>>();
  rownz_kernel<<<dim3(128), dim3(64), 0, stream>>>();
  scan_kernel<<<dim3(1), dim3(64), 0, stream>>>();
  select_gather_kernel<<<dim3(1), dim3(256), 0, stream>>>(out);
}

// Round 8
// 147.460 us; speedup vs baseline: 2.3129x; 1.0662x over previous
//
#include <hip/hip_runtime.h>
#include <math.h>

#define NBOX 8192
#define NW   128        // NBOX / 64
#define NF   9
#define MAXOUT 1024
#define IMG_H 360
#define IMG_W 1200
#define BEV_H 704
#define BEV_W 800
#define LDSROWS 56      // contested rows cached in LDS (56 KB); overflow reads global

// ---- persistent device scratch (module globals). Every element fully rewritten
// every call -> deterministic across graph replays.
__device__ float g_feat[NBOX * NF];
__device__ float g_score[NBOX];           // f32 softmax score (bit-mimics np)
__device__ float g_reg[NBOX * 6];
__device__ float g_obj[NBOX * 2];
__device__ float g_bev[NBOX * 4];         // unsorted bev boxes [z1,x1,z2,x2]
__device__ float g_sbev[NBOX * 4];        // sorted by rank
__device__ float g_sarea[NBOX];
__device__ int   g_rank[NBOX];
__device__ int   g_order[NBOX];           // rank -> original index
__device__ unsigned long long g_mask[(size_t)NBOX * NW];
__device__ unsigned long long g_rownz[NW];
__device__ unsigned long long g_kept[NW];

// correctly-rounded f32 exp (double internal, single final rounding)
__device__ __forceinline__ float expf_cr(float x) { return (float)exp((double)x); }

// ---- conv(1x1,32ch)+bias+relu, then mask multiply, at one pixel.
// Accumulation order mimics numpy einsum's SSE sum-of-products:
// 4 mod-4 lane accumulators, sequential group adds, reduce (L0+L1)+(L2+L3).
__device__ __forceinline__ float conv_relu_m(const float* __restrict__ map,
                                             const float* __restrict__ w,
                                             float bias, float mask,
                                             int y, int x, int W) {
  const float* p = map + ((size_t)y * W + x) * 32;
  float L0 = 0.0f, L1 = 0.0f, L2 = 0.0f, L3 = 0.0f;
#pragma unroll
  for (int c = 0; c < 32; c += 4) {
    L0 = __fadd_rn(L0, __fmul_rn(p[c + 0], w[c + 0]));
    L1 = __fadd_rn(L1, __fmul_rn(p[c + 1], w[c + 1]));
    L2 = __fadd_rn(L2, __fmul_rn(p[c + 2], w[c + 2]));
    L3 = __fadd_rn(L3, __fmul_rn(p[c + 3], w[c + 3]));
  }
  float A = __fadd_rn(L0, L1);
  float B = __fadd_rn(L2, L3);
  float conv = __fadd_rn(A, B);
  conv = __fadd_rn(conv, bias);
  float r = fmaxf(conv, 0.0f);
  return __fmul_rn(mask, r);              // (mask * x)[pixel], mask applied to map
}

// ---- one bilinear sample of the masked conv map, f32 ops in np expression order
__device__ __forceinline__ float sample_map(const float* __restrict__ map, int H, int W,
                                            const float* __restrict__ w, float bias, float mask,
                                            float y1, float x1, float y2, float x2,
                                            int gy, int gx) {
  const float tt0 = 0.0f, tt1 = 0.5f, tt2 = 1.0f;   // arange(3)/2 in f32, exact
  float ty = (gy == 0) ? tt0 : (gy == 1 ? tt1 : tt2);
  float tx = (gx == 0) ? tt0 : (gx == 1 ? tt1 : tt2);
  float ys = __fmul_rn(__fadd_rn(y1, __fmul_rn(__fsub_rn(y2, y1), ty)), (float)(H - 1));
  float xs = __fmul_rn(__fadd_rn(x1, __fmul_rn(__fsub_rn(x2, x1), tx)), (float)(W - 1));
  bool valid = (ys >= 0.0f) && (ys <= (float)(H - 1)) && (xs >= 0.0f) && (xs <= (float)(W - 1));
  if (!valid) return 0.0f;
  float y0 = floorf(ys), x0 = floorf(xs);
  float wy = __fsub_rn(ys, y0);
  float wx = __fsub_rn(xs, x0);
  int y0i = (int)fminf(fmaxf(y0, 0.0f), (float)(H - 1));
  int y1i = (int)fminf(fmaxf(__fadd_rn(y0, 1.0f), 0.0f), (float)(H - 1));
  int x0i = (int)fminf(fmaxf(x0, 0.0f), (float)(W - 1));
  int x1i = (int)fminf(fmaxf(__fadd_rn(x0, 1.0f), 0.0f), (float)(W - 1));
  float g00 = conv_relu_m(map, w, bias, mask, y0i, x0i, W);
  float g01 = conv_relu_m(map, w, bias, mask, y0i, x1i, W);
  float g10 = conv_relu_m(map, w, bias, mask, y1i, x0i, W);
  float g11 = conv_relu_m(map, w, bias, mask, y1i, x1i, W);
  float a = __fsub_rn(1.0f, wy);
  float b = __fsub_rn(1.0f, wx);
  float t1 = __fmul_rn(__fmul_rn(g00, a), b);
  float t2 = __fmul_rn(__fmul_rn(g01, a), wx);
  float t3 = __fmul_rn(__fmul_rn(g10, wy), b);
  float t4 = __fmul_rn(__fmul_rn(g11, wy), wx);
  return __fadd_rn(__fadd_rn(__fadd_rn(t1, t2), t3), t4);
}

// ---- K1: one thread per (box, sample); fused ROI feature (all f32) ----
__global__ __launch_bounds__(256) void roi_feat_kernel(
    const float* __restrict__ img_map, const float* __restrict__ bev_map,
    const float* __restrict__ anc_img, const float* __restrict__ anc_bev,
    const float* __restrict__ w_img, const float* __restrict__ b_img,
    const float* __restrict__ w_bev, const float* __restrict__ b_bev,
    const float* __restrict__ img_mask, const float* __restrict__ bev_mask) {
  int t = blockIdx.x * 256 + threadIdx.x;          // 73728 threads exactly
  int box = t / NF, s = t % NF;
  int gy = s / 3, gx = s % 3;
  const float* Ai = anc_img + (size_t)box * 5;     // cols: [0, x1, y1, x2, y2]
  const float* Ab = anc_bev + (size_t)box * 5;
  float mi = img_mask[0], mb = bev_mask[0];
  float vi = sample_map(img_map, IMG_H, IMG_W, w_img, b_img[0], mi,
                        Ai[2], Ai[1], Ai[4], Ai[3], gy, gx);
  float vb = sample_map(bev_map, BEV_H, BEV_W, w_bev, b_bev[0], mb,
                        Ab[2], Ab[1], Ab[4], Ab[3], gy, gx);
  g_feat[t] = __fdiv_rn(__fadd_rn(vi, vb), __fadd_rn(mi, mb));
}

// ---- K2: per-box head, f32 with BLAS-style sequential-FMA matmuls.
// Also zeroes g_rank and g_rownz for the passes that follow. ----
__global__ __launch_bounds__(256) void head_kernel(
    const float* __restrict__ fa,
    const float* __restrict__ w_obj, const float* __restrict__ b_obj,
    const float* __restrict__ w_off, const float* __restrict__ b_off) {
  int i = blockIdx.x * 256 + threadIdx.x;
  if (i >= NBOX) return;
  g_rank[i] = 0;
  if (i < NW) g_rownz[i] = 0ull;
  float f[NF];
#pragma unroll
  for (int k = 0; k < NF; ++k) f[k] = g_feat[(size_t)i * NF + k];

  float o0 = 0.0f, o1 = 0.0f;
#pragma unroll
  for (int k = 0; k < NF; ++k) {
    o0 = fmaf(f[k], w_obj[k * 2 + 0], o0);
    o1 = fmaf(f[k], w_obj[k * 2 + 1], o1);
  }
  o0 = __fadd_rn(o0, b_obj[0]);
  o1 = __fadd_rn(o1, b_obj[1]);

  float off[6];
#pragma unroll
  for (int m = 0; m < 6; ++m) {
    float s = 0.0f;
#pragma unroll
    for (int k = 0; k < NF; ++k) s = fmaf(f[k], w_off[k * 6 + m], s);
    off[m] = __fadd_rn(s, b_off[m]);
  }

  float reg[6];
#pragma unroll
  for (int k = 0; k < 3; ++k)
    reg[k] = __fadd_rn(fa[i * 6 + k], __fmul_rn(off[k], fa[i * 6 + 3 + k]));
#pragma unroll
  for (int k = 0; k < 3; ++k)
    reg[3 + k] = __fmul_rn(fa[i * 6 + 3 + k], expf_cr(off[3 + k]));

#pragma unroll
  for (int k = 0; k < 6; ++k) g_reg[i * 6 + k] = reg[k];
  g_obj[i * 2 + 0] = o0;
  g_obj[i * 2 + 1] = o1;

  // softmax(objectness)[:,1] in f32, np op order: max, sub, exp, sum, div
  float m  = fmaxf(o0, o1);
  float d0 = __fsub_rn(o0, m);
  float d1 = __fsub_rn(o1, m);
  float e0 = expf_cr(d0);
  float e1 = expf_cr(d1);
  float sm = __fadd_rn(e0, e1);
  g_score[i] = __fdiv_rn(e1, sm);

  float cx = reg[0], cz = reg[2], dx = reg[3], dz = reg[5];
  float dxh = __fdiv_rn(dx, 2.0f);
  float dzh = __fdiv_rn(dz, 2.0f);
  g_bev[i * 4 + 0] = __fsub_rn(70.0f, __fadd_rn(cz, dzh));              // bz1
  g_bev[i * 4 + 1] = __fsub_rn(__fsub_rn(cx, dxh), -40.0f);             // bx1
  g_bev[i * 4 + 2] = __fsub_rn(70.0f, __fsub_rn(cz, dzh));              // bz2
  g_bev[i * 4 + 3] = __fsub_rn(__fadd_rn(cx, dxh), -40.0f);             // bx2
}

// ---- K3: exact stable descending rank on f32 scores, 2-D tiled.
// Integer atomicAdd partial sums: associative -> deterministic. ----
__global__ __launch_bounds__(256) void rank_kernel() {
  __shared__ float kj[256];
  int tid = threadIdx.x;
  int i = blockIdx.x * 256 + tid;
  int jbase = blockIdx.y * 256;
  kj[tid] = g_score[jbase + tid];
  float ki = g_score[i];
  __syncthreads();
  int cnt = 0;
#pragma unroll 8
  for (int k = 0; k < 256; ++k) {
    float v = kj[k];
    int j = jbase + k;
    cnt += (v > ki) || (v == ki && j < i);
  }
  atomicAdd(&g_rank[i], cnt);
}

// ---- K3b: scatter to sorted order; area in f32 (np op order) ----
__global__ __launch_bounds__(256) void scatter_kernel() {
  int i = blockIdx.x * 256 + threadIdx.x;
  if (i >= NBOX) return;
  int r = g_rank[i];
  g_order[r] = i;
  float b0 = g_bev[i * 4 + 0], b1 = g_bev[i * 4 + 1];
  float b2 = g_bev[i * 4 + 2], b3 = g_bev[i * 4 + 3];
  g_sbev[r * 4 + 0] = b0; g_sbev[r * 4 + 1] = b1;
  g_sbev[r * 4 + 2] = b2; g_sbev[r * 4 + 3] = b3;
  g_sarea[r] = __fmul_rn(__fsub_rn(b2, b0), __fsub_rn(b3, b1));
}

// ---- K4: 64x64 IoU bitmask tiles in f32; lower triangle explicitly zeroed.
// Also accumulates g_rownz via atomicOr (order-independent -> deterministic). ----
__global__ __launch_bounds__(64) void mask_kernel() {
  int c = blockIdx.x, r = blockIdx.y;
  int lane = threadIdx.x;
  int i = r * 64 + lane;
  if (c < r) {
    g_mask[(size_t)i * NW + c] = 0ull;
    return;
  }
  __shared__ float sb[64 * 5];
  {
    int j = c * 64 + lane;
    sb[lane * 5 + 0] = g_sbev[j * 4 + 0];
    sb[lane * 5 + 1] = g_sbev[j * 4 + 1];
    sb[lane * 5 + 2] = g_sbev[j * 4 + 2];
    sb[lane * 5 + 3] = g_sbev[j * 4 + 3];
    sb[lane * 5 + 4] = g_sarea[j];
  }
  __syncthreads();
  float y1 = g_sbev[i * 4 + 0], x1 = g_sbev[i * 4 + 1];
  float y2 = g_sbev[i * 4 + 2], x2 = g_sbev[i * 4 + 3];
  float ai = g_sarea[i];
  unsigned long long bits = 0ull;
  int jbase = c * 64;
  for (int k = 0; k < 64; ++k) {
    int j = jbase + k;
    float by1 = sb[k * 5 + 0], bx1 = sb[k * 5 + 1];
    float by2 = sb[k * 5 + 2], bx2 = sb[k * 5 + 3], aj = sb[k * 5 + 4];
    // np op order: wh = max(br-tl,0); inter = wh0*wh1;
    // iou = inter / (ai + aj - inter + 1e-9); over = iou > 0.8
    float ih = fmaxf(__fsub_rn(fminf(y2, by2), fmaxf(y1, by1)), 0.0f);
    float iw = fmaxf(__fsub_rn(fminf(x2, bx2), fmaxf(x1, bx1)), 0.0f);
    float inter = __fmul_rn(ih, iw);
    float t1 = __fadd_rn(ai, aj);
    float t2 = __fsub_rn(t1, inter);
    float t3 = __fadd_rn(t2, 1e-9f);
    float iou = __fdiv_rn(inter, t3);
    bool over = (j > i) && (iou > 0.8f);
    bits |= over ? (1ull << k) : 0ull;
  }
  g_mask[(size_t)i * NW + c] = bits;
  if (bits) atomicOr(&g_rownz[i >> 6], 1ull << (i & 63));
}

// ---- K5: greedy scan. remv in registers (2 u64/lane, shfl for cross-lane);
// contested rows prefetched into LDS in parallel batches; only contested
// words visited (ballot bitmap). kept = ~remv written wholesale at end
// (valid: a row for box b only sets bits at columns >= word(b)). ----
__global__ __launch_bounds__(64) void scan_kernel() {
  __shared__ unsigned long long crow[LDSROWS * NW];   // 56 KB
  __shared__ unsigned long long rn_s[NW];
  __shared__ int base_s[NW];
  __shared__ int pos_s[LDSROWS];
  int lane = threadIdx.x;

  unsigned long long r0 = g_rownz[lane], r1 = g_rownz[64 + lane];
  rn_s[lane] = r0; rn_s[64 + lane] = r1;

  // exclusive prefix of per-word popcounts (word order: 0..63 = r0, 64..127 = r1)
  int pc0 = __popcll(r0), pc1 = __popcll(r1);
  int s0 = pc0, s1 = pc1;
#pragma unroll
  for (int d = 1; d < 64; d <<= 1) {
    int t0 = __shfl_up(s0, d, 64);
    int t1 = __shfl_up(s1, d, 64);
    if (lane >= d) { s0 += t0; s1 += t1; }
  }
  int total0 = __shfl(s0, 63, 64);
  int total  = total0 + __shfl(s1, 63, 64);
  base_s[lane]      = s0 - pc0;
  base_s[64 + lane] = total0 + (s1 - pc1);

  // contested position list (first LDSROWS slots)
  {
    unsigned long long m = r0; int idx = s0 - pc0;
    while (m) { int b = __builtin_ctzll(m); m &= m - 1;
                if (idx < LDSROWS) pos_s[idx] = lane * 64 + b; idx++; }
    m = r1; idx = total0 + (s1 - pc1);
    while (m) { int b = __builtin_ctzll(m); m &= m - 1;
                if (idx < LDSROWS) pos_s[idx] = (64 + lane) * 64 + b; idx++; }
  }
  __syncthreads();

  // batched parallel prefetch of contested rows into LDS (8 loads in flight)
  int nlds = total < LDSROWS ? total : LDSROWS;
  for (int t = 0; t < nlds; t += 4) {
    unsigned long long a0[4], a1[4];
#pragma unroll
    for (int k = 0; k < 4; ++k) {
      int tt = t + k;
      if (tt < nlds) {
        size_t p = (size_t)pos_s[tt];
        a0[k] = g_mask[p * NW + lane];
        a1[k] = g_mask[p * NW + 64 + lane];
      }
    }
#pragma unroll
    for (int k = 0; k < 4; ++k) {
      int tt = t + k;
      if (tt < nlds) {
        crow[tt * NW + lane]      = a0[k];
        crow[tt * NW + 64 + lane] = a1[k];
      }
    }
  }
  __syncthreads();

  // serial greedy scan over contested words only
  unsigned long long remv0 = 0ull, remv1 = 0ull;
  unsigned long long wnz0 = __ballot(r0 != 0ull);
  unsigned long long wnz1 = __ballot(r1 != 0ull);
#pragma unroll 1
  for (int g = 0; g < 2; ++g) {
    unsigned long long ww = (g == 0) ? wnz0 : wnz1;
    while (ww) {
      int wl = __builtin_ctzll(ww); ww &= ww - 1;
      int w = g * 64 + wl;
      unsigned long long rn  = rn_s[w];
      unsigned long long cur = (g == 0) ? __shfl(remv0, wl, 64) : __shfl(remv1, wl, 64);
      unsigned long long todo = rn & ~cur;
      int sbase = base_s[w];
      while (todo) {
        int b = __builtin_ctzll(todo); todo &= todo - 1;
        int s = sbase + __popcll(rn & ((1ull << b) - 1ull));
        if (s < LDSROWS) {
          remv0 |= crow[s * NW + lane];
          remv1 |= crow[s * NW + 64 + lane];
        } else {
          size_t p = (size_t)(w * 64 + b);
          remv0 |= g_mask[p * NW + lane];
          remv1 |= g_mask[p * NW + 64 + lane];
        }
        cur = (g == 0) ? __shfl(remv0, wl, 64) : __shfl(remv1, wl, 64);
        todo &= ~cur;
      }
    }
  }
  g_kept[lane]      = ~remv0;
  g_kept[64 + lane] = ~remv1;
}

// ---- K6: sel = kept positions asc, then suppressed asc; gather outputs ----
__global__ __launch_bounds__(256) void select_gather_kernel(float* __restrict__ out) {
  __shared__ int pk[NW], ps[NW];
  __shared__ int totK;
  __shared__ int tidx[MAXOUT];
  int tid = threadIdx.x;
  if (tid < NW) {
    pk[tid] = __popcll(g_kept[tid]);
    ps[tid] = 64 - pk[tid];
  }
  __syncthreads();
  if (tid == 0) {
    int s = 0;
    for (int w = 0; w < NW; ++w) { int t = pk[w]; pk[w] = s; s += t; }
    totK = s;
    s = 0;
    for (int w = 0; w < NW; ++w) { int t = ps[w]; ps[w] = s; s += t; }
  }
  __syncthreads();
  if (tid < NW) {
    unsigned long long kw = g_kept[tid];
    int rk = pk[tid], rs = totK + ps[tid];
    for (int b = 0; b < 64; ++b) {
      int pos = tid * 64 + b;
      if ((kw >> b) & 1ull) {
        if (rk < MAXOUT) tidx[rk] = g_order[pos];
        rk++;
      } else {
        if (rs < MAXOUT) tidx[rs] = g_order[pos];
        rs++;
      }
    }
  }
  __syncthreads();
  for (int k = tid; k < MAXOUT; k += 256) {
    int ti = tidx[k];
#pragma unroll
    for (int m = 0; m < 6; ++m) out[k * 6 + m] = g_reg[ti * 6 + m];
    out[MAXOUT * 6 + k * 2 + 0] = g_obj[ti * 2 + 0];
    out[MAXOUT * 6 + k * 2 + 1] = g_obj[ti * 2 + 1];
  }
}

extern "C" void kernel_launch(void* const* d_in, const int* in_sizes, int n_in,
                              void* d_out, int out_size, void* d_ws, size_t ws_size,
                              hipStream_t stream) {
  const float* img_map  = (const float*)d_in[0];
  const float* bev_map  = (const float*)d_in[1];
  const float* anc_img  = (const float*)d_in[2];
  const float* anc_bev  = (const float*)d_in[3];
  const float* fa       = (const float*)d_in[4];
  const float* w_img    = (const float*)d_in[5];
  const float* b_img    = (const float*)d_in[6];
  const float* w_bev    = (const float*)d_in[7];
  const float* b_bev    = (const float*)d_in[8];
  const float* w_obj    = (const float*)d_in[9];
  const float* b_obj    = (const float*)d_in[10];
  const float* w_off    = (const float*)d_in[11];
  const float* b_off    = (const float*)d_in[12];
  const float* img_mask = (const float*)d_in[13];
  const float* bev_mask = (const float*)d_in[14];
  float* out = (float*)d_out;

  roi_feat_kernel<<<dim3(288), dim3(256), 0, stream>>>(
      img_map, bev_map, anc_img, anc_bev, w_img, b_img, w_bev, b_bev, img_mask, bev_mask);
  head_kernel<<<dim3(32), dim3(256), 0, stream>>>(fa, w_obj, b_obj, w_off, b_off);
  rank_kernel<<<dim3(32, 32), dim3(256), 0, stream>>>();
  scatter_kernel<<<dim3(32), dim3(256), 0, stream>>>();
  mask_kernel<<<dim3(128, 128), dim3(64), 0, stream>>>();
  scan_kernel<<<dim3(1), dim3(64), 0, stream>>>();
  select_gather_kernel<<<dim3(1), dim3(256), 0, stream>>>(out);
}

// Round 9
// 120.289 us; speedup vs baseline: 2.8353x; 1.2259x over previous
//
#include <hip/hip_runtime.h>
#include <math.h>

#define NBOX 8192
#define NW   128        // NBOX / 64
#define NF   9
#define MAXOUT 1024
#define IMG_H 360
#define IMG_W 1200
#define BEV_H 704
#define BEV_W 800

// ---- persistent device scratch (module globals). Every element fully rewritten
// every call -> deterministic across graph replays.
__device__ float g_feat[NBOX * NF];
__device__ float g_score[NBOX];           // f32 softmax score (bit-mimics np)
__device__ float g_reg[NBOX * 6];
__device__ float g_obj[NBOX * 2];
__device__ float g_bev[NBOX * 4];         // unsorted bev boxes [z1,x1,z2,x2]
__device__ float g_sbev[NBOX * 4];        // sorted by rank
__device__ float g_sarea[NBOX];
__device__ int   g_rank[NBOX];
__device__ int   g_order[NBOX];           // rank -> original index
__device__ unsigned long long g_mask[(size_t)NBOX * NW];
__device__ unsigned long long g_rownz[NW];
__device__ unsigned long long g_kept[NW];

// correctly-rounded f32 exp (double internal, single final rounding)
__device__ __forceinline__ float expf_cr(float x) { return (float)exp((double)x); }

// ---- conv(1x1,32ch)+bias+relu, then mask multiply, at one pixel.
// Accumulation order mimics numpy einsum's SSE sum-of-products:
// 4 mod-4 lane accumulators, sequential group adds, reduce (L0+L1)+(L2+L3).
__device__ __forceinline__ float conv_relu_m(const float* __restrict__ map,
                                             const float* __restrict__ w,
                                             float bias, float mask,
                                             int y, int x, int W) {
  const float* p = map + ((size_t)y * W + x) * 32;
  float L0 = 0.0f, L1 = 0.0f, L2 = 0.0f, L3 = 0.0f;
#pragma unroll
  for (int c = 0; c < 32; c += 4) {
    L0 = __fadd_rn(L0, __fmul_rn(p[c + 0], w[c + 0]));
    L1 = __fadd_rn(L1, __fmul_rn(p[c + 1], w[c + 1]));
    L2 = __fadd_rn(L2, __fmul_rn(p[c + 2], w[c + 2]));
    L3 = __fadd_rn(L3, __fmul_rn(p[c + 3], w[c + 3]));
  }
  float A = __fadd_rn(L0, L1);
  float B = __fadd_rn(L2, L3);
  float conv = __fadd_rn(A, B);
  conv = __fadd_rn(conv, bias);
  float r = fmaxf(conv, 0.0f);
  return __fmul_rn(mask, r);              // (mask * x)[pixel], mask applied to map
}

// ---- one bilinear sample of the masked conv map, f32 ops in np expression order
__device__ __forceinline__ float sample_map(const float* __restrict__ map, int H, int W,
                                            const float* __restrict__ w, float bias, float mask,
                                            float y1, float x1, float y2, float x2,
                                            int gy, int gx) {
  const float tt0 = 0.0f, tt1 = 0.5f, tt2 = 1.0f;   // arange(3)/2 in f32, exact
  float ty = (gy == 0) ? tt0 : (gy == 1 ? tt1 : tt2);
  float tx = (gx == 0) ? tt0 : (gx == 1 ? tt1 : tt2);
  float ys = __fmul_rn(__fadd_rn(y1, __fmul_rn(__fsub_rn(y2, y1), ty)), (float)(H - 1));
  float xs = __fmul_rn(__fadd_rn(x1, __fmul_rn(__fsub_rn(x2, x1), tx)), (float)(W - 1));
  bool valid = (ys >= 0.0f) && (ys <= (float)(H - 1)) && (xs >= 0.0f) && (xs <= (float)(W - 1));
  if (!valid) return 0.0f;
  float y0 = floorf(ys), x0 = floorf(xs);
  float wy = __fsub_rn(ys, y0);
  float wx = __fsub_rn(xs, x0);
  int y0i = (int)fminf(fmaxf(y0, 0.0f), (float)(H - 1));
  int y1i = (int)fminf(fmaxf(__fadd_rn(y0, 1.0f), 0.0f), (float)(H - 1));
  int x0i = (int)fminf(fmaxf(x0, 0.0f), (float)(W - 1));
  int x1i = (int)fminf(fmaxf(__fadd_rn(x0, 1.0f), 0.0f), (float)(W - 1));
  float g00 = conv_relu_m(map, w, bias, mask, y0i, x0i, W);
  float g01 = conv_relu_m(map, w, bias, mask, y0i, x1i, W);
  float g10 = conv_relu_m(map, w, bias, mask, y1i, x0i, W);
  float g11 = conv_relu_m(map, w, bias, mask, y1i, x1i, W);
  float a = __fsub_rn(1.0f, wy);
  float b = __fsub_rn(1.0f, wx);
  float t1 = __fmul_rn(__fmul_rn(g00, a), b);
  float t2 = __fmul_rn(__fmul_rn(g01, a), wx);
  float t3 = __fmul_rn(__fmul_rn(g10, wy), b);
  float t4 = __fmul_rn(__fmul_rn(g11, wy), wx);
  return __fadd_rn(__fadd_rn(__fadd_rn(t1, t2), t3), t4);
}

// ---- K1: one thread per (box, sample); fused ROI feature (all f32) ----
__global__ __launch_bounds__(256) void roi_feat_kernel(
    const float* __restrict__ img_map, const float* __restrict__ bev_map,
    const float* __restrict__ anc_img, const float* __restrict__ anc_bev,
    const float* __restrict__ w_img, const float* __restrict__ b_img,
    const float* __restrict__ w_bev, const float* __restrict__ b_bev,
    const float* __restrict__ img_mask, const float* __restrict__ bev_mask) {
  int t = blockIdx.x * 256 + threadIdx.x;          // 73728 threads exactly
  int box = t / NF, s = t % NF;
  int gy = s / 3, gx = s % 3;
  const float* Ai = anc_img + (size_t)box * 5;     // cols: [0, x1, y1, x2, y2]
  const float* Ab = anc_bev + (size_t)box * 5;
  float mi = img_mask[0], mb = bev_mask[0];
  float vi = sample_map(img_map, IMG_H, IMG_W, w_img, b_img[0], mi,
                        Ai[2], Ai[1], Ai[4], Ai[3], gy, gx);
  float vb = sample_map(bev_map, BEV_H, BEV_W, w_bev, b_bev[0], mb,
                        Ab[2], Ab[1], Ab[4], Ab[3], gy, gx);
  g_feat[t] = __fdiv_rn(__fadd_rn(vi, vb), __fadd_rn(mi, mb));
}

// ---- K2: per-box head, f32 with BLAS-style sequential-FMA matmuls.
// Also zeroes g_rank and g_rownz for the passes that follow. ----
__global__ __launch_bounds__(256) void head_kernel(
    const float* __restrict__ fa,
    const float* __restrict__ w_obj, const float* __restrict__ b_obj,
    const float* __restrict__ w_off, const float* __restrict__ b_off) {
  int i = blockIdx.x * 256 + threadIdx.x;
  if (i >= NBOX) return;
  g_rank[i] = 0;
  if (i < NW) g_rownz[i] = 0ull;
  float f[NF];
#pragma unroll
  for (int k = 0; k < NF; ++k) f[k] = g_feat[(size_t)i * NF + k];

  float o0 = 0.0f, o1 = 0.0f;
#pragma unroll
  for (int k = 0; k < NF; ++k) {
    o0 = fmaf(f[k], w_obj[k * 2 + 0], o0);
    o1 = fmaf(f[k], w_obj[k * 2 + 1], o1);
  }
  o0 = __fadd_rn(o0, b_obj[0]);
  o1 = __fadd_rn(o1, b_obj[1]);

  float off[6];
#pragma unroll
  for (int m = 0; m < 6; ++m) {
    float s = 0.0f;
#pragma unroll
    for (int k = 0; k < NF; ++k) s = fmaf(f[k], w_off[k * 6 + m], s);
    off[m] = __fadd_rn(s, b_off[m]);
  }

  float reg[6];
#pragma unroll
  for (int k = 0; k < 3; ++k)
    reg[k] = __fadd_rn(fa[i * 6 + k], __fmul_rn(off[k], fa[i * 6 + 3 + k]));
#pragma unroll
  for (int k = 0; k < 3; ++k)
    reg[3 + k] = __fmul_rn(fa[i * 6 + 3 + k], expf_cr(off[3 + k]));

#pragma unroll
  for (int k = 0; k < 6; ++k) g_reg[i * 6 + k] = reg[k];
  g_obj[i * 2 + 0] = o0;
  g_obj[i * 2 + 1] = o1;

  // softmax(objectness)[:,1] in f32, np op order: max, sub, exp, sum, div
  float m  = fmaxf(o0, o1);
  float d0 = __fsub_rn(o0, m);
  float d1 = __fsub_rn(o1, m);
  float e0 = expf_cr(d0);
  float e1 = expf_cr(d1);
  float sm = __fadd_rn(e0, e1);
  g_score[i] = __fdiv_rn(e1, sm);

  float cx = reg[0], cz = reg[2], dx = reg[3], dz = reg[5];
  float dxh = __fdiv_rn(dx, 2.0f);
  float dzh = __fdiv_rn(dz, 2.0f);
  g_bev[i * 4 + 0] = __fsub_rn(70.0f, __fadd_rn(cz, dzh));              // bz1
  g_bev[i * 4 + 1] = __fsub_rn(__fsub_rn(cx, dxh), -40.0f);             // bx1
  g_bev[i * 4 + 2] = __fsub_rn(70.0f, __fsub_rn(cz, dzh));              // bz2
  g_bev[i * 4 + 3] = __fsub_rn(__fadd_rn(cx, dxh), -40.0f);             // bx2
}

// ---- K3: exact stable descending rank on f32 scores, 2-D tiled.
// Integer atomicAdd partial sums: associative -> deterministic. ----
__global__ __launch_bounds__(256) void rank_kernel() {
  __shared__ float kj[256];
  int tid = threadIdx.x;
  int i = blockIdx.x * 256 + tid;
  int jbase = blockIdx.y * 256;
  kj[tid] = g_score[jbase + tid];
  float ki = g_score[i];
  __syncthreads();
  int cnt = 0;
#pragma unroll 8
  for (int k = 0; k < 256; ++k) {
    float v = kj[k];
    int j = jbase + k;
    cnt += (v > ki) || (v == ki && j < i);
  }
  atomicAdd(&g_rank[i], cnt);
}

// ---- K3b: scatter to sorted order; area in f32 (np op order) ----
__global__ __launch_bounds__(256) void scatter_kernel() {
  int i = blockIdx.x * 256 + threadIdx.x;
  if (i >= NBOX) return;
  int r = g_rank[i];
  g_order[r] = i;
  float b0 = g_bev[i * 4 + 0], b1 = g_bev[i * 4 + 1];
  float b2 = g_bev[i * 4 + 2], b3 = g_bev[i * 4 + 3];
  g_sbev[r * 4 + 0] = b0; g_sbev[r * 4 + 1] = b1;
  g_sbev[r * 4 + 2] = b2; g_sbev[r * 4 + 3] = b3;
  g_sarea[r] = __fmul_rn(__fsub_rn(b2, b0), __fsub_rn(b3, b1));
}

// ---- K4: 64x64 IoU bitmask tiles in f32; lower triangle explicitly zeroed.
// Also accumulates g_rownz via atomicOr (order-independent -> deterministic). ----
__global__ __launch_bounds__(64) void mask_kernel() {
  int c = blockIdx.x, r = blockIdx.y;
  int lane = threadIdx.x;
  int i = r * 64 + lane;
  if (c < r) {
    g_mask[(size_t)i * NW + c] = 0ull;
    return;
  }
  __shared__ float sb[64 * 5];
  {
    int j = c * 64 + lane;
    sb[lane * 5 + 0] = g_sbev[j * 4 + 0];
    sb[lane * 5 + 1] = g_sbev[j * 4 + 1];
    sb[lane * 5 + 2] = g_sbev[j * 4 + 2];
    sb[lane * 5 + 3] = g_sbev[j * 4 + 3];
    sb[lane * 5 + 4] = g_sarea[j];
  }
  __syncthreads();
  float y1 = g_sbev[i * 4 + 0], x1 = g_sbev[i * 4 + 1];
  float y2 = g_sbev[i * 4 + 2], x2 = g_sbev[i * 4 + 3];
  float ai = g_sarea[i];
  unsigned long long bits = 0ull;
  int jbase = c * 64;
  for (int k = 0; k < 64; ++k) {
    int j = jbase + k;
    float by1 = sb[k * 5 + 0], bx1 = sb[k * 5 + 1];
    float by2 = sb[k * 5 + 2], bx2 = sb[k * 5 + 3], aj = sb[k * 5 + 4];
    // np op order: wh = max(br-tl,0); inter = wh0*wh1;
    // iou = inter / (ai + aj - inter + 1e-9); over = iou > 0.8
    float ih = fmaxf(__fsub_rn(fminf(y2, by2), fmaxf(y1, by1)), 0.0f);
    float iw = fmaxf(__fsub_rn(fminf(x2, bx2), fmaxf(x1, bx1)), 0.0f);
    float inter = __fmul_rn(ih, iw);
    float t1 = __fadd_rn(ai, aj);
    float t2 = __fsub_rn(t1, inter);
    float t3 = __fadd_rn(t2, 1e-9f);
    float iou = __fdiv_rn(inter, t3);
    bool over = (j > i) && (iou > 0.8f);
    bits |= over ? (1ull << k) : 0ull;
  }
  g_mask[(size_t)i * NW + c] = bits;
  if (bits) atomicOr(&g_rownz[i >> 6], 1ull << (i & 63));
}

// ---- K5: greedy scan. remv in registers (2 u64/lane); ALL contested rows
// speculatively prefetched through a triple-buffered register pipeline
// (static indices -> no scratch). Serial chain per row = shfl + test + OR. ----
#define LOAD_CHUNK(X0, X1, T0)                                          \
  _Pragma("unroll")                                                     \
  for (int k = 0; k < 8; ++k) {                                         \
    int tt = (T0) + k;                                                  \
    unsigned long long a = 0ull, b = 0ull;                              \
    if (tt < total) {                                                   \
      size_t p = (size_t)pos_s[tt];                                     \
      a = g_mask[p * NW + lane];                                        \
      b = g_mask[p * NW + 64 + lane];                                   \
    }                                                                   \
    X0[k] = a; X1[k] = b;                                               \
  }

#define PROC_CHUNK(X0, X1, T0)                                          \
  _Pragma("unroll")                                                     \
  for (int k = 0; k < 8; ++k) {                                         \
    int tt = (T0) + k;                                                  \
    int p  = pos_s[tt];                                                 \
    int w  = p >> 6, bb = p & 63;                                       \
    unsigned long long cw = (w < 64) ? __shfl(remv0, w, 64)             \
                                     : __shfl(remv1, w - 64, 64);       \
    if (tt < total && !((cw >> bb) & 1ull)) {                           \
      remv0 |= X0[k]; remv1 |= X1[k];                                   \
    }                                                                   \
  }

__global__ __launch_bounds__(64) void scan_kernel() {
  __shared__ unsigned short pos_s[NBOX + 64];
  int lane = threadIdx.x;

  unsigned long long r0 = g_rownz[lane], r1 = g_rownz[64 + lane];

  // exclusive prefix of per-word popcounts (word order: 0..63 = r0, 64..127 = r1)
  int pc0 = __popcll(r0), pc1 = __popcll(r1);
  int s0 = pc0, s1 = pc1;
#pragma unroll
  for (int d = 1; d < 64; d <<= 1) {
    int t0 = __shfl_up(s0, d, 64);
    int t1 = __shfl_up(s1, d, 64);
    if (lane >= d) { s0 += t0; s1 += t1; }
  }
  int total0 = __shfl(s0, 63, 64);
  int total  = total0 + __shfl(s1, 63, 64);

  // ascending contested-position list
  {
    unsigned long long m = r0; int idx = s0 - pc0;
    while (m) { int b = __builtin_ctzll(m); m &= m - 1;
                pos_s[idx++] = (unsigned short)(lane * 64 + b); }
    m = r1; idx = total0 + (s1 - pc1);
    while (m) { int b = __builtin_ctzll(m); m &= m - 1;
                pos_s[idx++] = (unsigned short)((64 + lane) * 64 + b); }
  }
  pos_s[total + lane] = 0;                 // pad so unguarded PROC reads are safe
  __syncthreads();

  unsigned long long remv0 = 0ull, remv1 = 0ull;
  unsigned long long A0[8], A1[8], B0[8], B1[8], C0[8], C1[8];

  LOAD_CHUNK(A0, A1, 0)
  LOAD_CHUNK(B0, B1, 8)
  LOAD_CHUNK(C0, C1, 16)
  for (int t0 = 0; t0 < total; t0 += 24) {
    PROC_CHUNK(A0, A1, t0)
    LOAD_CHUNK(A0, A1, t0 + 24)
    PROC_CHUNK(B0, B1, t0 + 8)
    LOAD_CHUNK(B0, B1, t0 + 32)
    PROC_CHUNK(C0, C1, t0 + 16)
    LOAD_CHUNK(C0, C1, t0 + 40)
  }

  g_kept[lane]      = ~remv0;
  g_kept[64 + lane] = ~remv1;
}

// ---- K6: sel = kept positions asc, then suppressed asc; gather outputs ----
__global__ __launch_bounds__(256) void select_gather_kernel(float* __restrict__ out) {
  __shared__ int pk[NW], ps[NW];
  __shared__ int totK;
  __shared__ int tidx[MAXOUT];
  int tid = threadIdx.x;
  if (tid < NW) {
    pk[tid] = __popcll(g_kept[tid]);
    ps[tid] = 64 - pk[tid];
  }
  __syncthreads();
  if (tid == 0) {
    int s = 0;
    for (int w = 0; w < NW; ++w) { int t = pk[w]; pk[w] = s; s += t; }
    totK = s;
    s = 0;
    for (int w = 0; w < NW; ++w) { int t = ps[w]; ps[w] = s; s += t; }
  }
  __syncthreads();
  if (tid < NW) {
    unsigned long long kw = g_kept[tid];
    int rk = pk[tid], rs = totK + ps[tid];
    for (int b = 0; b < 64; ++b) {
      int pos = tid * 64 + b;
      if ((kw >> b) & 1ull) {
        if (rk < MAXOUT) tidx[rk] = g_order[pos];
        rk++;
      } else {
        if (rs < MAXOUT) tidx[rs] = g_order[pos];
        rs++;
      }
    }
  }
  __syncthreads();
  for (int k = tid; k < MAXOUT; k += 256) {
    int ti = tidx[k];
#pragma unroll
    for (int m = 0; m < 6; ++m) out[k * 6 + m] = g_reg[ti * 6 + m];
    out[MAXOUT * 6 + k * 2 + 0] = g_obj[ti * 2 + 0];
    out[MAXOUT * 6 + k * 2 + 1] = g_obj[ti * 2 + 1];
  }
}

extern "C" void kernel_launch(void* const* d_in, const int* in_sizes, int n_in,
                              void* d_out, int out_size, void* d_ws, size_t ws_size,
                              hipStream_t stream) {
  const float* img_map  = (const float*)d_in[0];
  const float* bev_map  = (const float*)d_in[1];
  const float* anc_img  = (const float*)d_in[2];
  const float* anc_bev  = (const float*)d_in[3];
  const float* fa       = (const float*)d_in[4];
  const float* w_img    = (const float*)d_in[5];
  const float* b_img    = (const float*)d_in[6];
  const float* w_bev    = (const float*)d_in[7];
  const float* b_bev    = (const float*)d_in[8];
  const float* w_obj    = (const float*)d_in[9];
  const float* b_obj    = (const float*)d_in[10];
  const float* w_off    = (const float*)d_in[11];
  const float* b_off    = (const float*)d_in[12];
  const float* img_mask = (const float*)d_in[13];
  const float* bev_mask = (const float*)d_in[14];
  float* out = (float*)d_out;

  roi_feat_kernel<<<dim3(288), dim3(256), 0, stream>>>(
      img_map, bev_map, anc_img, anc_bev, w_img, b_img, w_bev, b_bev, img_mask, bev_mask);
  head_kernel<<<dim3(32), dim3(256), 0, stream>>>(fa, w_obj, b_obj, w_off, b_off);
  rank_kernel<<<dim3(32, 32), dim3(256), 0, stream>>>();
  scatter_kernel<<<dim3(32), dim3(256), 0, stream>>>();
  mask_kernel<<<dim3(128, 128), dim3(64), 0, stream>>>();
  scan_kernel<<<dim3(1), dim3(64), 0, stream>>>();
  select_gather_kernel<<<dim3(1), dim3(256), 0, stream>>>(out);
}

// Round 10
// 112.080 us; speedup vs baseline: 3.0430x; 1.0732x over previous
//
#include <hip/hip_runtime.h>
#include <math.h>

#define NBOX 8192
#define NW   128        // NBOX / 64
#define NF   9
#define MAXOUT 1024
#define IMG_H 360
#define IMG_W 1200
#define BEV_H 704
#define BEV_W 800

// ---- persistent device scratch (module globals). Every element fully rewritten
// every call -> deterministic across graph replays.
__device__ float g_feat[NBOX * NF];
__device__ float g_score[NBOX];           // f32 softmax score (bit-mimics np)
__device__ float g_reg[NBOX * 6];
__device__ float g_obj[NBOX * 2];
__device__ float g_bev[NBOX * 4];         // unsorted bev boxes [z1,x1,z2,x2]
__device__ float g_sbev[NBOX * 4];        // sorted by rank
__device__ float g_sarea[NBOX];
__device__ int   g_rank[NBOX];
__device__ int   g_order[NBOX];           // rank -> original index
__device__ unsigned long long g_mask[(size_t)NBOX * NW];
__device__ unsigned long long g_rownz[NW];
__device__ unsigned long long g_kept[NW];

// correctly-rounded f32 exp (double internal, single final rounding)
__device__ __forceinline__ float expf_cr(float x) { return (float)exp((double)x); }

// ---- conv(1x1,32ch)+bias+relu, then mask multiply, at one pixel.
// Accumulation order mimics numpy einsum's SSE sum-of-products:
// 4 mod-4 lane accumulators, sequential group adds, reduce (L0+L1)+(L2+L3).
__device__ __forceinline__ float conv_relu_m(const float* __restrict__ map,
                                             const float* __restrict__ w,
                                             float bias, float mask,
                                             int y, int x, int W) {
  const float* p = map + ((size_t)y * W + x) * 32;
  float L0 = 0.0f, L1 = 0.0f, L2 = 0.0f, L3 = 0.0f;
#pragma unroll
  for (int c = 0; c < 32; c += 4) {
    L0 = __fadd_rn(L0, __fmul_rn(p[c + 0], w[c + 0]));
    L1 = __fadd_rn(L1, __fmul_rn(p[c + 1], w[c + 1]));
    L2 = __fadd_rn(L2, __fmul_rn(p[c + 2], w[c + 2]));
    L3 = __fadd_rn(L3, __fmul_rn(p[c + 3], w[c + 3]));
  }
  float A = __fadd_rn(L0, L1);
  float B = __fadd_rn(L2, L3);
  float conv = __fadd_rn(A, B);
  conv = __fadd_rn(conv, bias);
  float r = fmaxf(conv, 0.0f);
  return __fmul_rn(mask, r);              // (mask * x)[pixel], mask applied to map
}

// ---- K1: 8 threads per (box, sample): sub 0-3 img pixels, 4-7 bev pixels.
// Each thread evaluates one conv_relu pixel (bit-exact); sub==0 combines with
// the exact f32 chain of the reference. ----
__global__ __launch_bounds__(256) void roi_feat_kernel(
    const float* __restrict__ img_map, const float* __restrict__ bev_map,
    const float* __restrict__ anc_img, const float* __restrict__ anc_bev,
    const float* __restrict__ w_img, const float* __restrict__ b_img,
    const float* __restrict__ w_bev, const float* __restrict__ b_bev,
    const float* __restrict__ img_mask, const float* __restrict__ bev_mask) {
  __shared__ float sg[32][12];            // [0..7]=pixel vals, [8]=wyB,[9]=wxB,[10]=validB
  int tid = threadIdx.x;
  int grp = tid >> 3, sub = tid & 7;
  int gidx = blockIdx.x * 32 + grp;       // = box*9 + s;  2304*32 = 73728 exactly
  int box = gidx / NF, s = gidx % NF;
  int gy = s / 3, gx = s % 3;
  bool isImg = (sub < 4);

  float mi = img_mask[0], mb = bev_mask[0];
  const float* A   = (isImg ? anc_img : anc_bev) + (size_t)box * 5;  // [0,x1,y1,x2,y2]
  const float* map = isImg ? img_map : bev_map;
  const float* wv  = isImg ? w_img : w_bev;
  float bias = isImg ? b_img[0] : b_bev[0];
  float mk   = isImg ? mi : mb;
  int H = isImg ? IMG_H : BEV_H;
  int W = isImg ? IMG_W : BEV_W;
  float y1 = A[2], x1 = A[1], y2 = A[4], x2 = A[3];

  const float tt0 = 0.0f, tt1 = 0.5f, tt2 = 1.0f;   // arange(3)/2 in f32, exact
  float ty = (gy == 0) ? tt0 : (gy == 1 ? tt1 : tt2);
  float tx = (gx == 0) ? tt0 : (gx == 1 ? tt1 : tt2);
  float ys = __fmul_rn(__fadd_rn(y1, __fmul_rn(__fsub_rn(y2, y1), ty)), (float)(H - 1));
  float xs = __fmul_rn(__fadd_rn(x1, __fmul_rn(__fsub_rn(x2, x1), tx)), (float)(W - 1));
  bool valid = (ys >= 0.0f) && (ys <= (float)(H - 1)) && (xs >= 0.0f) && (xs <= (float)(W - 1));
  float y0 = floorf(ys), x0 = floorf(xs);
  float wy = __fsub_rn(ys, y0);
  float wx = __fsub_rn(xs, x0);
  int y0i = (int)fminf(fmaxf(y0, 0.0f), (float)(H - 1));
  int y1i = (int)fminf(fmaxf(__fadd_rn(y0, 1.0f), 0.0f), (float)(H - 1));
  int x0i = (int)fminf(fmaxf(x0, 0.0f), (float)(W - 1));
  int x1i = (int)fminf(fmaxf(__fadd_rn(x0, 1.0f), 0.0f), (float)(W - 1));

  int py = (sub & 2) ? y1i : y0i;         // pixel: 0:(y0,x0) 1:(y0,x1) 2:(y1,x0) 3:(y1,x1)
  int px = (sub & 1) ? x1i : x0i;
  // clamped indices are always in-range, so the load is safe even when !valid
  sg[grp][sub] = conv_relu_m(map, wv, bias, mk, py, px, W);
  if (sub == 4) {
    sg[grp][8]  = wy;
    sg[grp][9]  = wx;
    sg[grp][10] = valid ? 1.0f : 0.0f;
  }
  __syncthreads();
  if (sub == 0) {
    float vi = 0.0f;
    if (valid) {                           // img validity (this thread is an img thread)
      float a = __fsub_rn(1.0f, wy);
      float b = __fsub_rn(1.0f, wx);
      float t1 = __fmul_rn(__fmul_rn(sg[grp][0], a), b);
      float t2 = __fmul_rn(__fmul_rn(sg[grp][1], a), wx);
      float t3 = __fmul_rn(__fmul_rn(sg[grp][2], wy), b);
      float t4 = __fmul_rn(__fmul_rn(sg[grp][3], wy), wx);
      vi = __fadd_rn(__fadd_rn(__fadd_rn(t1, t2), t3), t4);
    }
    float vb = 0.0f;
    if (sg[grp][10] != 0.0f) {
      float wyB = sg[grp][8], wxB = sg[grp][9];
      float a = __fsub_rn(1.0f, wyB);
      float b = __fsub_rn(1.0f, wxB);
      float t1 = __fmul_rn(__fmul_rn(sg[grp][4], a), b);
      float t2 = __fmul_rn(__fmul_rn(sg[grp][5], a), wxB);
      float t3 = __fmul_rn(__fmul_rn(sg[grp][6], wyB), b);
      float t4 = __fmul_rn(__fmul_rn(sg[grp][7], wyB), wxB);
      vb = __fadd_rn(__fadd_rn(__fadd_rn(t1, t2), t3), t4);
    }
    g_feat[gidx] = __fdiv_rn(__fadd_rn(vi, vb), __fadd_rn(mi, mb));
  }
}

// ---- K2: per-box head, f32 with BLAS-style sequential-FMA matmuls.
// Also zeroes g_rank and g_rownz for the passes that follow. ----
__global__ __launch_bounds__(256) void head_kernel(
    const float* __restrict__ fa,
    const float* __restrict__ w_obj, const float* __restrict__ b_obj,
    const float* __restrict__ w_off, const float* __restrict__ b_off) {
  int i = blockIdx.x * 256 + threadIdx.x;
  if (i >= NBOX) return;
  g_rank[i] = 0;
  if (i < NW) g_rownz[i] = 0ull;
  float f[NF];
#pragma unroll
  for (int k = 0; k < NF; ++k) f[k] = g_feat[(size_t)i * NF + k];

  float o0 = 0.0f, o1 = 0.0f;
#pragma unroll
  for (int k = 0; k < NF; ++k) {
    o0 = fmaf(f[k], w_obj[k * 2 + 0], o0);
    o1 = fmaf(f[k], w_obj[k * 2 + 1], o1);
  }
  o0 = __fadd_rn(o0, b_obj[0]);
  o1 = __fadd_rn(o1, b_obj[1]);

  float off[6];
#pragma unroll
  for (int m = 0; m < 6; ++m) {
    float s = 0.0f;
#pragma unroll
    for (int k = 0; k < NF; ++k) s = fmaf(f[k], w_off[k * 6 + m], s);
    off[m] = __fadd_rn(s, b_off[m]);
  }

  float reg[6];
#pragma unroll
  for (int k = 0; k < 3; ++k)
    reg[k] = __fadd_rn(fa[i * 6 + k], __fmul_rn(off[k], fa[i * 6 + 3 + k]));
#pragma unroll
  for (int k = 0; k < 3; ++k)
    reg[3 + k] = __fmul_rn(fa[i * 6 + 3 + k], expf_cr(off[3 + k]));

#pragma unroll
  for (int k = 0; k < 6; ++k) g_reg[i * 6 + k] = reg[k];
  g_obj[i * 2 + 0] = o0;
  g_obj[i * 2 + 1] = o1;

  // softmax(objectness)[:,1] in f32, np op order: max, sub, exp, sum, div
  float m  = fmaxf(o0, o1);
  float d0 = __fsub_rn(o0, m);
  float d1 = __fsub_rn(o1, m);
  float e0 = expf_cr(d0);
  float e1 = expf_cr(d1);
  float sm = __fadd_rn(e0, e1);
  g_score[i] = __fdiv_rn(e1, sm);

  float cx = reg[0], cz = reg[2], dx = reg[3], dz = reg[5];
  float dxh = __fdiv_rn(dx, 2.0f);
  float dzh = __fdiv_rn(dz, 2.0f);
  g_bev[i * 4 + 0] = __fsub_rn(70.0f, __fadd_rn(cz, dzh));              // bz1
  g_bev[i * 4 + 1] = __fsub_rn(__fsub_rn(cx, dxh), -40.0f);             // bx1
  g_bev[i * 4 + 2] = __fsub_rn(70.0f, __fsub_rn(cz, dzh));              // bz2
  g_bev[i * 4 + 3] = __fsub_rn(__fadd_rn(cx, dxh), -40.0f);             // bx2
}

// ---- K3: exact stable descending rank on f32 scores, 2-D tiled.
// Integer atomicAdd partial sums: associative -> deterministic. ----
__global__ __launch_bounds__(256) void rank_kernel() {
  __shared__ float kj[256];
  int tid = threadIdx.x;
  int i = blockIdx.x * 256 + tid;
  int jbase = blockIdx.y * 256;
  kj[tid] = g_score[jbase + tid];
  float ki = g_score[i];
  __syncthreads();
  int cnt = 0;
#pragma unroll 8
  for (int k = 0; k < 256; ++k) {
    float v = kj[k];
    int j = jbase + k;
    cnt += (v > ki) || (v == ki && j < i);
  }
  atomicAdd(&g_rank[i], cnt);
}

// ---- K3b: scatter to sorted order; area in f32 (np op order) ----
__global__ __launch_bounds__(256) void scatter_kernel() {
  int i = blockIdx.x * 256 + threadIdx.x;
  if (i >= NBOX) return;
  int r = g_rank[i];
  g_order[r] = i;
  float b0 = g_bev[i * 4 + 0], b1 = g_bev[i * 4 + 1];
  float b2 = g_bev[i * 4 + 2], b3 = g_bev[i * 4 + 3];
  g_sbev[r * 4 + 0] = b0; g_sbev[r * 4 + 1] = b1;
  g_sbev[r * 4 + 2] = b2; g_sbev[r * 4 + 3] = b3;
  g_sarea[r] = __fmul_rn(__fsub_rn(b2, b0), __fsub_rn(b3, b1));
}

// ---- K4: 64x64 IoU bitmask tiles in f32; lower triangle explicitly zeroed.
// Also accumulates g_rownz via atomicOr (order-independent -> deterministic). ----
__global__ __launch_bounds__(64) void mask_kernel() {
  int c = blockIdx.x, r = blockIdx.y;
  int lane = threadIdx.x;
  int i = r * 64 + lane;
  if (c < r) {
    g_mask[(size_t)i * NW + c] = 0ull;
    return;
  }
  __shared__ float sb[64 * 5];
  {
    int j = c * 64 + lane;
    sb[lane * 5 + 0] = g_sbev[j * 4 + 0];
    sb[lane * 5 + 1] = g_sbev[j * 4 + 1];
    sb[lane * 5 + 2] = g_sbev[j * 4 + 2];
    sb[lane * 5 + 3] = g_sbev[j * 4 + 3];
    sb[lane * 5 + 4] = g_sarea[j];
  }
  __syncthreads();
  float y1 = g_sbev[i * 4 + 0], x1 = g_sbev[i * 4 + 1];
  float y2 = g_sbev[i * 4 + 2], x2 = g_sbev[i * 4 + 3];
  float ai = g_sarea[i];
  unsigned long long bits = 0ull;
  int jbase = c * 64;
  for (int k = 0; k < 64; ++k) {
    int j = jbase + k;
    float by1 = sb[k * 5 + 0], bx1 = sb[k * 5 + 1];
    float by2 = sb[k * 5 + 2], bx2 = sb[k * 5 + 3], aj = sb[k * 5 + 4];
    // np op order: wh = max(br-tl,0); inter = wh0*wh1;
    // iou = inter / (ai + aj - inter + 1e-9); over = iou > 0.8
    float ih = fmaxf(__fsub_rn(fminf(y2, by2), fmaxf(y1, by1)), 0.0f);
    float iw = fmaxf(__fsub_rn(fminf(x2, bx2), fmaxf(x1, bx1)), 0.0f);
    float inter = __fmul_rn(ih, iw);
    float t1 = __fadd_rn(ai, aj);
    float t2 = __fsub_rn(t1, inter);
    float t3 = __fadd_rn(t2, 1e-9f);
    float iou = __fdiv_rn(inter, t3);
    bool over = (j > i) && (iou > 0.8f);
    bits |= over ? (1ull << k) : 0ull;
  }
  g_mask[(size_t)i * NW + c] = bits;
  if (bits) atomicOr(&g_rownz[i >> 6], 1ull << (i & 63));
}

// ---- K5: greedy scan. remv in registers (2 u64/lane); ALL contested rows
// speculatively prefetched through a triple-buffered register pipeline
// (static indices -> no scratch). Serial chain per row = shfl + test + OR. ----
#define LOAD_CHUNK(X0, X1, T0)                                          \
  _Pragma("unroll")                                                     \
  for (int k = 0; k < 8; ++k) {                                         \
    int tt = (T0) + k;                                                  \
    unsigned long long a = 0ull, b = 0ull;                              \
    if (tt < total) {                                                   \
      size_t p = (size_t)pos_s[tt];                                     \
      a = g_mask[p * NW + lane];                                        \
      b = g_mask[p * NW + 64 + lane];                                   \
    }                                                                   \
    X0[k] = a; X1[k] = b;                                               \
  }

#define PROC_CHUNK(X0, X1, T0)                                          \
  _Pragma("unroll")                                                     \
  for (int k = 0; k < 8; ++k) {                                         \
    int tt = (T0) + k;                                                  \
    int p  = pos_s[tt];                                                 \
    int w  = p >> 6, bb = p & 63;                                       \
    unsigned long long cw = (w < 64) ? __shfl(remv0, w, 64)             \
                                     : __shfl(remv1, w - 64, 64);       \
    if (tt < total && !((cw >> bb) & 1ull)) {                           \
      remv0 |= X0[k]; remv1 |= X1[k];                                   \
    }                                                                   \
  }

__global__ __launch_bounds__(64) void scan_kernel() {
  __shared__ unsigned short pos_s[NBOX + 64];
  int lane = threadIdx.x;

  unsigned long long r0 = g_rownz[lane], r1 = g_rownz[64 + lane];

  // exclusive prefix of per-word popcounts (word order: 0..63 = r0, 64..127 = r1)
  int pc0 = __popcll(r0), pc1 = __popcll(r1);
  int s0 = pc0, s1 = pc1;
#pragma unroll
  for (int d = 1; d < 64; d <<= 1) {
    int t0 = __shfl_up(s0, d, 64);
    int t1 = __shfl_up(s1, d, 64);
    if (lane >= d) { s0 += t0; s1 += t1; }
  }
  int total0 = __shfl(s0, 63, 64);
  int total  = total0 + __shfl(s1, 63, 64);

  // ascending contested-position list
  {
    unsigned long long m = r0; int idx = s0 - pc0;
    while (m) { int b = __builtin_ctzll(m); m &= m - 1;
                pos_s[idx++] = (unsigned short)(lane * 64 + b); }
    m = r1; idx = total0 + (s1 - pc1);
    while (m) { int b = __builtin_ctzll(m); m &= m - 1;
                pos_s[idx++] = (unsigned short)((64 + lane) * 64 + b); }
  }
  pos_s[total + lane] = 0;                 // pad so unguarded PROC reads are safe
  __syncthreads();

  unsigned long long remv0 = 0ull, remv1 = 0ull;
  unsigned long long A0[8], A1[8], B0[8], B1[8], C0[8], C1[8];

  LOAD_CHUNK(A0, A1, 0)
  LOAD_CHUNK(B0, B1, 8)
  LOAD_CHUNK(C0, C1, 16)
  for (int t0 = 0; t0 < total; t0 += 24) {
    PROC_CHUNK(A0, A1, t0)
    LOAD_CHUNK(A0, A1, t0 + 24)
    PROC_CHUNK(B0, B1, t0 + 8)
    LOAD_CHUNK(B0, B1, t0 + 32)
    PROC_CHUNK(C0, C1, t0 + 16)
    LOAD_CHUNK(C0, C1, t0 + 40)
  }

  g_kept[lane]      = ~remv0;
  g_kept[64 + lane] = ~remv1;
}

// ---- K6: sel = kept positions asc, then suppressed asc; gather outputs ----
__global__ __launch_bounds__(256) void select_gather_kernel(float* __restrict__ out) {
  __shared__ int pk[NW], ps[NW];
  __shared__ int totK;
  __shared__ int tidx[MAXOUT];
  int tid = threadIdx.x;
  if (tid < NW) {
    pk[tid] = __popcll(g_kept[tid]);
    ps[tid] = 64 - pk[tid];
  }
  __syncthreads();
  if (tid == 0) {
    int s = 0;
    for (int w = 0; w < NW; ++w) { int t = pk[w]; pk[w] = s; s += t; }
    totK = s;
    s = 0;
    for (int w = 0; w < NW; ++w) { int t = ps[w]; ps[w] = s; s += t; }
  }
  __syncthreads();
  if (tid < NW) {
    unsigned long long kw = g_kept[tid];
    int rk = pk[tid], rs = totK + ps[tid];
    for (int b = 0; b < 64; ++b) {
      int pos = tid * 64 + b;
      if ((kw >> b) & 1ull) {
        if (rk < MAXOUT) tidx[rk] = g_order[pos];
        rk++;
      } else {
        if (rs < MAXOUT) tidx[rs] = g_order[pos];
        rs++;
      }
    }
  }
  __syncthreads();
  for (int k = tid; k < MAXOUT; k += 256) {
    int ti = tidx[k];
#pragma unroll
    for (int m = 0; m < 6; ++m) out[k * 6 + m] = g_reg[ti * 6 + m];
    out[MAXOUT * 6 + k * 2 + 0] = g_obj[ti * 2 + 0];
    out[MAXOUT * 6 + k * 2 + 1] = g_obj[ti * 2 + 1];
  }
}

extern "C" void kernel_launch(void* const* d_in, const int* in_sizes, int n_in,
                              void* d_out, int out_size, void* d_ws, size_t ws_size,
                              hipStream_t stream) {
  const float* img_map  = (const float*)d_in[0];
  const float* bev_map  = (const float*)d_in[1];
  const float* anc_img  = (const float*)d_in[2];
  const float* anc_bev  = (const float*)d_in[3];
  const float* fa       = (const float*)d_in[4];
  const float* w_img    = (const float*)d_in[5];
  const float* b_img    = (const float*)d_in[6];
  const float* w_bev    = (const float*)d_in[7];
  const float* b_bev    = (const float*)d_in[8];
  const float* w_obj    = (const float*)d_in[9];
  const float* b_obj    = (const float*)d_in[10];
  const float* w_off    = (const float*)d_in[11];
  const float* b_off    = (const float*)d_in[12];
  const float* img_mask = (const float*)d_in[13];
  const float* bev_mask = (const float*)d_in[14];
  float* out = (float*)d_out;

  roi_feat_kernel<<<dim3(2304), dim3(256), 0, stream>>>(
      img_map, bev_map, anc_img, anc_bev, w_img, b_img, w_bev, b_bev, img_mask, bev_mask);
  head_kernel<<<dim3(32), dim3(256), 0, stream>>>(fa, w_obj, b_obj, w_off, b_off);
  rank_kernel<<<dim3(32, 32), dim3(256), 0, stream>>>();
  scatter_kernel<<<dim3(32), dim3(256), 0, stream>>>();
  mask_kernel<<<dim3(128, 128), dim3(64), 0, stream>>>();
  scan_kernel<<<dim3(1), dim3(64), 0, stream>>>();
  select_gather_kernel<<<dim3(1), dim3(256), 0, stream>>>(out);
}